// Round 12
// baseline (78.620 us; speedup 1.0000x reference)
//
#include <hip/hip_runtime.h>
#include <hip/hip_fp16.h>

#define VOCAB 100000
#define EMB   20
#define HID   10
#define SEQ   100
#define NLAB  15
#define BATCH 16384
#define GATES 40
#define PROWH 48   // halfs/row (96 B): slots u*4+G for u<10; slots 40-47 = 0

typedef _Float16 f16x8 __attribute__((ext_vector_type(8)));
typedef __fp16   fp16x2 __attribute__((ext_vector_type(2)));
typedef float    f32x4 __attribute__((ext_vector_type(4)));

__device__ __forceinline__ float exp2_f(float x){ float r; asm("v_exp_f32 %0, %1" : "=v"(r) : "v"(x)); return r; }
__device__ __forceinline__ float rcp_f(float x){ float r; asm("v_rcp_f32 %0, %1" : "=v"(r) : "v"(x)); return r; }

// Gate scales folded into P/Wh': sigmoid(x)=rcp(1+exp2(-log2e*x)),
// tanh(x)=(1-E)/(1+E), E=exp2(-2log2e*x). c-gate scale -2log2e, others -log2e.
__device__ __host__ __forceinline__ constexpr float gscale(int G){
  return (G == 2) ? -2.885390081777927f : -1.442695040888963f;
}

template<int CTRL>
__device__ __forceinline__ float qb(float x){
  return __int_as_float(__builtin_amdgcn_mov_dpp(__float_as_int(x), CTRL, 0xF, 0xF, true));
}

__device__ __forceinline__ unsigned pk16(float a, float b){
  union { fp16x2 v; unsigned u; } x;
  x.v = __builtin_amdgcn_cvt_pkrtz(a, b);
  return x.u;
}

// one LSTM unit's activation chain; z = (zi,zf,zc,zo) pre-scaled
__device__ __forceinline__ float actstep(f32x4 z, float& c){
  float Ei = exp2_f(z[0]);
  float Ef = exp2_f(z[1]);
  float Ec = exp2_f(fminf(z[2], 60.f));
  float Eo = exp2_f(z[3]);
  float f  = rcp_f(1.f + Ef);
  float ig = (1.f - Ec) * rcp_f((1.f + Ei) * (1.f + Ec));   // sigmoid(i)*tanh(c~)
  c = fmaf(f, c, ig);                                        // c = f*c + i*g
  float Et = exp2_f(fminf(-2.885390081777927f * c, 60.f));
  return (1.f - Et) * rcp_f((1.f + Eo) * (1.f + Et));        // h = o*tanh(c)
}

// -------- P = fp16( (embed @ Wx + b) * gate_scale ), 48-half rows, slots>=40 zero
__global__ __launch_bounds__(256)
void proj_kernel_h(const float* __restrict__ emb, const float* __restrict__ Wx,
                   const float* __restrict__ bias, __half* __restrict__ P)
{
  __shared__ float Wxl[EMB * GATES];   // [k][slot], slot = u*4+G
  __shared__ float bl[GATES];
  const int tid = threadIdx.x;
  for (int i = tid; i < EMB * GATES; i += 256) {
    int k = i / GATES, slot = i - k * GATES;
    int u = slot >> 2, G = slot & 3;
    Wxl[i] = Wx[k * GATES + G * HID + u] * gscale(G);
  }
  if (tid < GATES) {
    int u = tid >> 2, G = tid & 3;
    bl[tid] = bias[G * HID + u] * gscale(G);
  }
  __syncthreads();

  const int v   = blockIdx.x * 64 + (tid >> 2);
  const int sub = tid & 3;              // 12 slots each
  if (v >= VOCAB) return;

  const float4* er = (const float4*)(emb + (size_t)v * EMB);
  float4 e0 = er[0], e1 = er[1], e2 = er[2], e3 = er[3], e4 = er[4];
  float e[EMB] = {e0.x,e0.y,e0.z,e0.w, e1.x,e1.y,e1.z,e1.w, e2.x,e2.y,e2.z,e2.w,
                  e3.x,e3.y,e3.z,e3.w, e4.x,e4.y,e4.z,e4.w};

  float acc[12];
  #pragma unroll
  for (int c = 0; c < 12; ++c) {
    int slot = 12 * sub + c;
    acc[c] = (slot < GATES) ? bl[slot] : 0.f;
  }
  #pragma unroll
  for (int k = 0; k < EMB; ++k)
    #pragma unroll
    for (int c = 0; c < 12; ++c) {
      int slot = 12 * sub + c;
      if (slot < GATES) acc[c] = fmaf(e[k], Wxl[k * GATES + slot], acc[c]);
    }

  union { __half h[12]; uint2 u2[3]; } um;
  #pragma unroll
  for (int c = 0; c < 12; ++c) um.h[c] = __float2half(acc[c]);
  uint2* o = (uint2*)(P + (size_t)v * PROWH + 12 * sub);
  o[0] = um.u2[0]; o[1] = um.u2[1]; o[2] = um.u2[2];
}

// -------- MFMA LSTM: 1 wave = 16 elements. z[40x16] = Wh'[40x10]@h[10x16] via
// 3x mfma_f32_16x16x32_f16 (A=weights const, B=h fp16, C=P fp16->f32).
// D layout (verified): col=lane&15=elem, row=(lane>>4)*4+reg=gate -> with unit-major
// slots, lane (hi,e) holds complete units {hi, 4+hi, 8+hi} -> lane-local activations.
__global__ __launch_bounds__(256, 1)
void rnn_mfma_kernel(const int* __restrict__ x, const __half* __restrict__ P,
                     const float* __restrict__ Wh, const float* __restrict__ Wd,
                     const float* __restrict__ bd, float* __restrict__ out)
{
  __shared__ int   xs[64 * SEQ];              // 25600 B
  __shared__ float hbuf[64][12];              // final h per element (f32)

  const int tid = threadIdx.x;
  const int w   = tid >> 6;        // wave 0..3
  const int l   = tid & 63;
  const int hi  = l >> 4;
  const int e   = l & 15;
  const int b0  = blockIdx.x * 64;

  for (int i = tid; i < 64 * SEQ; i += 256) xs[i] = x[(size_t)b0 * SEQ + i];

  // A fragments (constant): A[m=g-16mi][k], lane: m=e(=l&15), k=8*hi+j (j=0..7)
  f16x8 Af[3];
  #pragma unroll
  for (int mi = 0; mi < 3; ++mi) {
    const int g = 16 * mi + e;                // gate slot this lane's A-row covers
    #pragma unroll
    for (int j = 0; j < 8; ++j) {
      const int kk = 8 * hi + j;
      float v = 0.f;
      if (g < GATES && kk < HID)
        v = Wh[kk * GATES + (g & 3) * HID + (g >> 2)] * gscale(g & 3);
      Af[mi][j] = (_Float16)v;
    }
  }

  __syncthreads();

  const int* myx = xs + (w * 16 + e) * SEQ;   // broadcast across the 4 hi-lanes

  // bpermute addresses (lane index * 4), constant
  const int a0 = e << 2, a1 = (e + 16) << 2, a2 = (e + 32) << 2, a3 = (e + 48) << 2;

  f16x8 B = {};                                // h = 0
  float c0 = 0.f, c1 = 0.f, c2 = 0.f;
  float hf0 = 0.f, hf1 = 0.f, hf2 = 0.f;       // last f32 h (for head)

  uint2 pA[3], pB[3];
  auto ldp = [&](uint2 (&p)[3], int t) {
    int tt = t < SEQ ? t : SEQ - 1;
    const char* rp = (const char*)P + (size_t)myx[tt] * (PROWH * 2);
    p[0] = *(const uint2*)(rp +      8 * hi);
    p[1] = *(const uint2*)(rp + 32 + 8 * hi);
    p[2] = *(const uint2*)(rp + 64 + 8 * hi);
  };
  ldp(pA, 0); ldp(pB, 1);

  auto mkC = [&](uint2 m) -> f32x4 {
    float2 lo = __half22float2(*(const __half2*)&m.x);
    float2 hi2 = __half22float2(*(const __half2*)&m.y);
    f32x4 r; r[0] = lo.x; r[1] = lo.y; r[2] = hi2.x; r[3] = hi2.y;
    return r;
  };

  auto step = [&](uint2 (&p)[3], int t) {
    f32x4 C0 = mkC(p[0]), C1 = mkC(p[1]), C2 = mkC(p[2]);
    ldp(p, t + 2);                             // depth-2 prefetch

    f32x4 z0 = __builtin_amdgcn_mfma_f32_16x16x32_f16(Af[0], B, C0, 0, 0, 0);
    f32x4 z1 = __builtin_amdgcn_mfma_f32_16x16x32_f16(Af[1], B, C1, 0, 0, 0);
    f32x4 z2 = __builtin_amdgcn_mfma_f32_16x16x32_f16(Af[2], B, C2, 0, 0, 0);

    hf0 = actstep(z0, c0);                     // unit hi
    hf1 = actstep(z1, c1);                     // unit 4+hi
    hf2 = actstep(z2, c2);                     // unit 8+hi (real for hi<2; else 0-path)

    // rebuild B fragment: lane needs h[k=8hi+j][e]; only k<10 matters (A zero-padded)
    unsigned pr = pk16(hf0, hf1);              // (h_hi, h_{4+hi})
    unsigned pc = pk16(hf2, hf2);
    unsigned b0v = __builtin_amdgcn_ds_bpermute(a0, (int)pr);   // (h0,h4)
    unsigned b1v = __builtin_amdgcn_ds_bpermute(a1, (int)pr);   // (h1,h5)
    unsigned b2v = __builtin_amdgcn_ds_bpermute(a2, (int)pr);   // (h2,h6)
    unsigned b3v = __builtin_amdgcn_ds_bpermute(a3, (int)pr);   // (h3,h7)
    unsigned c0v = __builtin_amdgcn_ds_bpermute(a0, (int)pc);   // (h8,·)
    unsigned c1v = __builtin_amdgcn_ds_bpermute(a1, (int)pc);   // (h9,·)
    unsigned r0 = __builtin_amdgcn_perm(b1v, b0v, 0x05040100u); // (h0,h1)
    unsigned r1 = __builtin_amdgcn_perm(b3v, b2v, 0x05040100u); // (h2,h3)
    unsigned r2 = __builtin_amdgcn_perm(b1v, b0v, 0x07060302u); // (h4,h5)
    unsigned r3 = __builtin_amdgcn_perm(b3v, b2v, 0x07060302u); // (h6,h7)
    unsigned r8 = __builtin_amdgcn_perm(c1v, c0v, 0x05040100u); // (h8,h9)
    if (hi == 1) r0 = r8;                      // hi=1 lanes carry k=8,9; rest don't-care
    union { unsigned u[4]; f16x8 v; } bb;
    bb.u[0] = r0; bb.u[1] = r1; bb.u[2] = r2; bb.u[3] = r3;
    B = bb.v;
  };

  #pragma unroll 1
  for (int t = 0; t < SEQ; t += 2) {           // SEQ even: 50 iterations
    step(pA, t);
    step(pB, t + 1);
  }

  // final h (f32) -> LDS, then dense head
  float* hr = hbuf[w * 16 + e];
  hr[hi] = hf0;
  hr[4 + hi] = hf1;
  if (hi < 2) hr[8 + hi] = hf2;
  __syncthreads();

  float hh[HID];
  #pragma unroll
  for (int k = 0; k < HID; ++k) hh[k] = hr[k];
  #pragma unroll
  for (int s = 0; s < 4; ++s) {
    int j = hi + 4 * s;
    if (j < NLAB) {
      float acc = bd[j];
      #pragma unroll
      for (int k = 0; k < HID; ++k)
        acc = fmaf(hh[k], Wd[k * NLAB + j], acc);
      out[(size_t)(b0 + w * 16 + e) * NLAB + j] = acc;
    }
  }
}

// -------- fallback (ws too small): 4-lane on-the-fly f32 path (proven)
__global__ __launch_bounds__(256, 1)
void rnn_kernel_fb(const int* __restrict__ x, const float* __restrict__ emb,
                   const float* __restrict__ Wx, const float* __restrict__ Wh,
                   const float* __restrict__ bias, const float* __restrict__ Wd,
                   const float* __restrict__ bd, float* __restrict__ out)
{
  __shared__ int   xs[64 * SEQ];
  __shared__ float Wxl[EMB * 48];
  __shared__ float bls[48];
  const int tid = threadIdx.x, lb = tid >> 2, sub = tid & 3, b0 = blockIdx.x * 64;
  for (int i = tid; i < 64 * SEQ; i += 256) xs[i] = x[(size_t)b0 * SEQ + i];
  for (int i = tid; i < EMB * 48; i += 256) {
    int k = i / 48, slot = i - k * 48;
    int sb2 = slot / 12, r = slot - sb2 * 12, G = r / 3, s = r - G * 3, u = s * 4 + sb2;
    Wxl[i] = (u < HID) ? Wx[k * GATES + G * HID + u] * gscale(G) : 0.f;
  }
  if (tid < 48) {
    int slot = tid, sb2 = slot / 12, r = slot - sb2 * 12, G = r / 3, s = r - G * 3, u = s * 4 + sb2;
    bls[slot] = (u < HID) ? bias[G * HID + u] * gscale(G) : 0.f;
  }
  float Whr[HID][12];
  #pragma unroll
  for (int j = 0; j < 12; ++j) {
    const int G = j / 3, s = j - G * 3, u = s * 4 + sub;
    #pragma unroll
    for (int k = 0; k < HID; ++k)
      Whr[k][j] = (u < HID) ? Wh[k * GATES + G * HID + u] * gscale(G) : 0.f;
  }
  __syncthreads();
  float cst[3] = {0.f, 0.f, 0.f};
  float h[HID];
  #pragma unroll
  for (int k = 0; k < HID; ++k) h[k] = 0.f;
  float bb[12];
  #pragma unroll
  for (int j = 0; j < 12; ++j) bb[j] = bls[sub * 12 + j];
  const int* xrow = xs + lb * SEQ;
  float4 e0, e1, e2, e3, e4;
  {
    int row = xrow[0];
    const float4* q = (const float4*)(emb + (size_t)row * EMB);
    e0 = q[0]; e1 = q[1]; e2 = q[2]; e3 = q[3]; e4 = q[4];
  }
  #pragma unroll 1
  for (int t = 0; t < SEQ; ++t) {
    float e[EMB] = {e0.x,e0.y,e0.z,e0.w, e1.x,e1.y,e1.z,e1.w, e2.x,e2.y,e2.z,e2.w,
                    e3.x,e3.y,e3.z,e3.w, e4.x,e4.y,e4.z,e4.w};
    float z[12];
    #pragma unroll
    for (int j = 0; j < 12; ++j) z[j] = bb[j];
    #pragma unroll
    for (int k = 0; k < EMB; ++k)
      #pragma unroll
      for (int j = 0; j < 12; ++j)
        z[j] = fmaf(e[k], Wxl[k * 48 + sub * 12 + j], z[j]);
    if (t + 1 < SEQ) {
      int row = xrow[t + 1];
      const float4* q = (const float4*)(emb + (size_t)row * EMB);
      e0 = q[0]; e1 = q[1]; e2 = q[2]; e3 = q[3]; e4 = q[4];
    }
    #pragma unroll
    for (int k = 0; k < HID; ++k)
      #pragma unroll
      for (int j = 0; j < 12; ++j)
        z[j] = fmaf(h[k], Whr[k][j], z[j]);
    float hl[3];
    #pragma unroll
    for (int s = 0; s < 3; ++s) {
      float Ei = exp2_f(z[s]), Ef = exp2_f(z[s+3]);
      float Ec = exp2_f(fminf(z[s+6], 60.f)), Eo = exp2_f(z[s+9]);
      float f  = rcp_f(1.f + Ef);
      float ig = (1.f - Ec) * rcp_f((1.f + Ei) * (1.f + Ec));
      cst[s] = fmaf(f, cst[s], ig);
      float Et = exp2_f(fminf(-2.885390081777927f * cst[s], 60.f));
      hl[s] = (1.f - Et) * rcp_f((1.f + Eo) * (1.f + Et));
    }
    h[0] = qb<0x00>(hl[0]); h[1] = qb<0x55>(hl[0]); h[2] = qb<0xAA>(hl[0]); h[3] = qb<0xFF>(hl[0]);
    h[4] = qb<0x00>(hl[1]); h[5] = qb<0x55>(hl[1]); h[6] = qb<0xAA>(hl[1]); h[7] = qb<0xFF>(hl[1]);
    h[8] = qb<0x00>(hl[2]); h[9] = qb<0x55>(hl[2]);
  }
  #pragma unroll
  for (int s = 0; s < 4; ++s) {
    int j = s * 4 + sub;
    if (j < NLAB) {
      float acc = bd[j];
      #pragma unroll
      for (int k = 0; k < HID; ++k)
        acc = fmaf(h[k], Wd[k * NLAB + j], acc);
      out[(size_t)(b0 + lb) * NLAB + j] = acc;
    }
  }
}

extern "C" void kernel_launch(void* const* d_in, const int* in_sizes, int n_in,
                              void* d_out, int out_size, void* d_ws, size_t ws_size,
                              hipStream_t stream) {
  (void)in_sizes; (void)n_in; (void)out_size;
  const int*   x    = (const int*)  d_in[0];
  const float* emb  = (const float*)d_in[1];
  const float* Wx   = (const float*)d_in[2];
  const float* Wh   = (const float*)d_in[3];
  const float* bias = (const float*)d_in[4];
  const float* Wd   = (const float*)d_in[5];
  const float* bd   = (const float*)d_in[6];
  float* out = (float*)d_out;

  const size_t pbytes = (size_t)VOCAB * PROWH * sizeof(__half);   // 9.6 MB
  if (ws_size >= pbytes) {
    __half* P = (__half*)d_ws;
    hipLaunchKernelGGL(proj_kernel_h, dim3((VOCAB + 63) / 64), dim3(256), 0, stream,
                       emb, Wx, bias, P);
    hipLaunchKernelGGL(rnn_mfma_kernel, dim3(BATCH / 64), dim3(256), 0, stream,
                       x, P, Wh, Wd, bd, out);
  } else {
    hipLaunchKernelGGL(rnn_kernel_fb, dim3(BATCH / 64), dim3(256), 0, stream,
                       x, emb, Wx, Wh, bias, Wd, bd, out);
  }
}